// Round 8
// baseline (67.728 us; speedup 1.0000x reference)
//
#include <hip/hip_runtime.h>
#include <hip/hip_bf16.h>

// 25-level wavelet decomposition, f: 2^25 f32, P: [25,2] f32.
// out layout: out[0]=final approx; detail level j occupies [2^(24-j), 2^(25-j)).
//
// R7: wave-autonomous k1 -- ZERO barriers, ZERO LDS in the streaming kernel.
// Each wave owns 1024 consecutive elements; each lane 16 consecutive:
//   levels 0-3 in registers (detail stores packed f4/f4/f2/f1),
//   levels 4-9 via 6 __shfl steps (wave-local, no sync),
//   wave approx -> out[wg] (wg<32768; region [0,2^15) fully rewritten by k2).
// k2 (1 block, 1024 threads = 16 waves): same trick for levels 10-20
//   (lane holds 32 consecutive: 5 reg levels + 6 shuffle levels), one
//   __syncthreads (drains all loads block-wide BEFORE detail stores that
//   overlap the input region [0,2^15)), then 16->1 shuffle tail 21-24.
//
// HISTORY:
//  R2-R4: 465us regression = __threadfence() L2 writeback storm (not nt).
//  R4: fused last-block election loses ~10us (2048 same-line atomics).
//  R5: nt stores alone neutral; keep on bulk bands. FETCH ~66MB (L3 serves half).
//  R6: CHUNK halving neutral -> lockstep tail halving didn't pay; this round
//      removes the barrier/LDS cascade entirely (k1: ~4.2 TB/s, VALUBusy 17%,
//      nothing saturated => latency-in-cascade theory).

#define THREADS 256
#define K1_BLOCKS ((1 << 25) / 1024 / 4)   // 8192 blocks, 4 waves each
#define K2THREADS 1024

typedef __attribute__((ext_vector_type(4))) float f4_t;
typedef __attribute__((ext_vector_type(2))) float f2_t;

__device__ __forceinline__ void nt_store4(float a, float b, float c, float d, float* p) {
    f4_t t = {a, b, c, d};
    __builtin_nontemporal_store(t, (f4_t*)p);
}
__device__ __forceinline__ void nt_store2(float a, float b, float* p) {
    f2_t t = {a, b};
    __builtin_nontemporal_store(t, (f2_t*)p);
}
__device__ __forceinline__ void nt_store1(float v, float* p) {
    __builtin_nontemporal_store(v, p);
}

__device__ __forceinline__ void level_params(const float* __restrict__ P, int j,
                                             float& hx, float& hy) {
    float px = P[2 * j], py = P[2 * j + 1];
    float n = fmaxf(sqrtf(px * px + py * py), 1e-12f);
    hx = px / n;  // phi_x
    hy = py / n;  // phi_y   (psi = (phi_y, -phi_x))
}

__global__ __launch_bounds__(THREADS, 4)
void wave_k1(const float* __restrict__ f, const float* __restrict__ P,
             float* __restrict__ out) {
    const int lane = threadIdx.x & 63;
    const int wid  = threadIdx.x >> 6;
    const int wg   = blockIdx.x * 4 + wid;     // global wave id, < 32768

    float hx[10], hy[10];
#pragma unroll
    for (int j = 0; j < 10; ++j) level_params(P, j, hx[j], hy[j]);

    // lane owns 16 consecutive elements: 4x float4
    const float4* in4 = reinterpret_cast<const float4*>(f) + (size_t)wg * 256 + lane * 4;
    float4 q0 = in4[0], q1 = in4[1], q2 = in4[2], q3 = in4[3];

    // ---- level 0: 8 details, 8 approx ----
    float a0 = q0.x*hx[0]+q0.y*hy[0], a1 = q0.z*hx[0]+q0.w*hy[0];
    float a2 = q1.x*hx[0]+q1.y*hy[0], a3 = q1.z*hx[0]+q1.w*hy[0];
    float a4 = q2.x*hx[0]+q2.y*hy[0], a5 = q2.z*hx[0]+q2.w*hy[0];
    float a6 = q3.x*hx[0]+q3.y*hy[0], a7 = q3.z*hx[0]+q3.w*hy[0];
    {
        float* b = out + (1 << 24) + wg * 512 + lane * 8;
        nt_store4(q0.x*hy[0]-q0.y*hx[0], q0.z*hy[0]-q0.w*hx[0],
                  q1.x*hy[0]-q1.y*hx[0], q1.z*hy[0]-q1.w*hx[0], b);
        nt_store4(q2.x*hy[0]-q2.y*hx[0], q2.z*hy[0]-q2.w*hx[0],
                  q3.x*hy[0]-q3.y*hx[0], q3.z*hy[0]-q3.w*hx[0], b + 4);
    }
    // ---- level 1: 4 details, 4 approx ----
    float b0 = a0*hx[1]+a1*hy[1], b1 = a2*hx[1]+a3*hy[1];
    float b2 = a4*hx[1]+a5*hy[1], b3 = a6*hx[1]+a7*hy[1];
    nt_store4(a0*hy[1]-a1*hx[1], a2*hy[1]-a3*hx[1],
              a4*hy[1]-a5*hx[1], a6*hy[1]-a7*hx[1],
              out + (1 << 23) + wg * 256 + lane * 4);
    // ---- level 2: 2 details, 2 approx ----
    float c0 = b0*hx[2]+b1*hy[2], c1 = b2*hx[2]+b3*hy[2];
    nt_store2(b0*hy[2]-b1*hx[2], b2*hy[2]-b3*hx[2],
              out + (1 << 22) + wg * 128 + lane * 2);
    // ---- level 3: 1 detail, 1 approx ----
    nt_store1(c0*hy[3]-c1*hx[3], out + (1 << 21) + wg * 64 + lane);
    float v = c0*hx[3]+c1*hy[3];

    // ---- levels 4..9: wave-local shuffles (no barriers) ----
#pragma unroll
    for (int j = 4; j <= 9; ++j) {
        int p = 1 << (9 - j);                 // 32,16,8,4,2,1
        float x = __shfl(v, 2 * lane, 64);
        float y = __shfl(v, 2 * lane + 1, 64);
        if (lane < p) out[(1 << (24 - j)) + wg * p + lane] = x*hy[j] - y*hx[j];
        v = x*hx[j] + y*hy[j];
    }
    if (lane == 0) out[wg] = v;               // temp; k2 rewrites [0, 2^15)
}

__global__ __launch_bounds__(K2THREADS)
void wave_k2(const float* __restrict__ P, float* __restrict__ out) {
    __shared__ float S[16];
    const int lane = threadIdx.x & 63;
    const int w    = threadIdx.x >> 6;        // 0..15

    float hx[15], hy[15];                     // levels 10..24 -> idx j-10
#pragma unroll
    for (int j = 10; j <= 24; ++j) level_params(P, j, hx[j - 10], hy[j - 10]);

    // wave owns 2048 of the 32768 approxes; lane owns 32 consecutive
    const float4* in4 = reinterpret_cast<const float4*>(out) + w * 512 + lane * 8;
    float4 q0 = in4[0], q1 = in4[1], q2 = in4[2], q3 = in4[3];
    float4 q4 = in4[4], q5 = in4[5], q6 = in4[6], q7 = in4[7];
    // Detail bands for levels 10-11 overlap the input region [0,2^15):
    // barrier (drains vmcnt block-wide) before ANY store below.
    __syncthreads();

    // ---- level 10: 16 details, 16 approx ----
    float a0 = q0.x*hx[0]+q0.y*hy[0], a1 = q0.z*hx[0]+q0.w*hy[0];
    float a2 = q1.x*hx[0]+q1.y*hy[0], a3 = q1.z*hx[0]+q1.w*hy[0];
    float a4 = q2.x*hx[0]+q2.y*hy[0], a5 = q2.z*hx[0]+q2.w*hy[0];
    float a6 = q3.x*hx[0]+q3.y*hy[0], a7 = q3.z*hx[0]+q3.w*hy[0];
    float a8 = q4.x*hx[0]+q4.y*hy[0], a9 = q4.z*hx[0]+q4.w*hy[0];
    float aA = q5.x*hx[0]+q5.y*hy[0], aB = q5.z*hx[0]+q5.w*hy[0];
    float aC = q6.x*hx[0]+q6.y*hy[0], aD = q6.z*hx[0]+q6.w*hy[0];
    float aE = q7.x*hx[0]+q7.y*hy[0], aF = q7.z*hx[0]+q7.w*hy[0];
    {
        float* b = out + (1 << 14) + w * 1024 + lane * 16;
        nt_store4(q0.x*hy[0]-q0.y*hx[0], q0.z*hy[0]-q0.w*hx[0],
                  q1.x*hy[0]-q1.y*hx[0], q1.z*hy[0]-q1.w*hx[0], b);
        nt_store4(q2.x*hy[0]-q2.y*hx[0], q2.z*hy[0]-q2.w*hx[0],
                  q3.x*hy[0]-q3.y*hx[0], q3.z*hy[0]-q3.w*hx[0], b + 4);
        nt_store4(q4.x*hy[0]-q4.y*hx[0], q4.z*hy[0]-q4.w*hx[0],
                  q5.x*hy[0]-q5.y*hx[0], q5.z*hy[0]-q5.w*hx[0], b + 8);
        nt_store4(q6.x*hy[0]-q6.y*hx[0], q6.z*hy[0]-q6.w*hx[0],
                  q7.x*hy[0]-q7.y*hx[0], q7.z*hy[0]-q7.w*hx[0], b + 12);
    }
    // ---- level 11: 8 details, 8 approx ----
    float b0 = a0*hx[1]+a1*hy[1], b1 = a2*hx[1]+a3*hy[1];
    float b2 = a4*hx[1]+a5*hy[1], b3 = a6*hx[1]+a7*hy[1];
    float b4 = a8*hx[1]+a9*hy[1], b5 = aA*hx[1]+aB*hy[1];
    float b6 = aC*hx[1]+aD*hy[1], b7 = aE*hx[1]+aF*hy[1];
    {
        float* b = out + (1 << 13) + w * 512 + lane * 8;
        nt_store4(a0*hy[1]-a1*hx[1], a2*hy[1]-a3*hx[1],
                  a4*hy[1]-a5*hx[1], a6*hy[1]-a7*hx[1], b);
        nt_store4(a8*hy[1]-a9*hx[1], aA*hy[1]-aB*hx[1],
                  aC*hy[1]-aD*hx[1], aE*hy[1]-aF*hx[1], b + 4);
    }
    // ---- level 12: 4 details, 4 approx ----
    float c0 = b0*hx[2]+b1*hy[2], c1 = b2*hx[2]+b3*hy[2];
    float c2 = b4*hx[2]+b5*hy[2], c3 = b6*hx[2]+b7*hy[2];
    nt_store4(b0*hy[2]-b1*hx[2], b2*hy[2]-b3*hx[2],
              b4*hy[2]-b5*hx[2], b6*hy[2]-b7*hx[2],
              out + (1 << 12) + w * 256 + lane * 4);
    // ---- level 13: 2 details, 2 approx ----
    float d0 = c0*hx[3]+c1*hy[3], d1 = c2*hx[3]+c3*hy[3];
    nt_store2(c0*hy[3]-c1*hx[3], c2*hy[3]-c3*hx[3],
              out + (1 << 11) + w * 128 + lane * 2);
    // ---- level 14: 1 detail, 1 approx ----
    nt_store1(d0*hy[4]-d1*hx[4], out + (1 << 10) + w * 64 + lane);
    float v = d0*hx[4]+d1*hy[4];

    // ---- levels 15..20: wave-local shuffles ----
#pragma unroll
    for (int j = 15; j <= 20; ++j) {
        int p = 1 << (20 - j);                // 32,16,8,4,2,1
        float x = __shfl(v, 2 * lane, 64);
        float y = __shfl(v, 2 * lane + 1, 64);
        if (lane < p) out[(1 << (24 - j)) + w * p + lane] = x*hy[j-10] - y*hx[j-10];
        v = x*hx[j-10] + y*hy[j-10];
    }
    if (lane == 0) S[w] = v;
    __syncthreads();

    // ---- levels 21..24: wave 0, 16 -> 1 ----
    if (w == 0) {
        float t = (lane < 16) ? S[lane] : 0.0f;
#pragma unroll
        for (int j = 21; j <= 24; ++j) {
            int p = 1 << (24 - j);            // 8,4,2,1
            float x = __shfl(t, 2 * lane, 64);
            float y = __shfl(t, 2 * lane + 1, 64);
            if (lane < p) out[p + lane] = x*hy[j-10] - y*hx[j-10];
            t = x*hx[j-10] + y*hy[j-10];
        }
        if (lane == 0) out[0] = t;
    }
}

extern "C" void kernel_launch(void* const* d_in, const int* in_sizes, int n_in,
                              void* d_out, int out_size, void* d_ws, size_t ws_size,
                              hipStream_t stream) {
    const float* f = (const float*)d_in[0];
    const float* P = (const float*)d_in[1];
    float* out = (float*)d_out;

    wave_k1<<<K1_BLOCKS, THREADS, 0, stream>>>(f, P, out);
    wave_k2<<<1, K2THREADS, 0, stream>>>(P, out);
}

// Round 9
// 53.459 us; speedup vs baseline: 1.2669x; 1.2669x over previous
//
#include <hip/hip_runtime.h>
#include <hip/hip_bf16.h>

// 25-level wavelet decomposition, f: 2^25 f32, P: [25,2] f32.
// out layout: out[0]=final approx; detail level j occupies [2^(24-j), 2^(25-j)).
//
// R8: barrier-free k1 (zero LDS, zero __syncthreads) with STRIDED-PAIR lane
// ownership so every detail-store instruction is contiguous across the wave:
//   lane loads q_k = in4[lane + 64k] (each float4 = 2 input pairs)
//   -> levels 0-1 lane-local (float2 / float detail stores, contiguous),
//   -> levels 2-3 via 2-reg shuffle-combine (contiguous scalar stores),
//   -> levels 4-9 via the 6-step shuffle tail.
// Wave approx -> out[wg] (temp; [0,2^15) fully rewritten by k2).
// k2: 1 block x 1024 thr, same structure for levels 10-20 (8 regs/lane),
//   one barrier after loads (L10/11 bands overlap input), shuffle tail 21-24.
//
// HISTORY:
//  R2-R4: 465us = __threadfence() L2 writeback storm (not nt stores).
//  R5: nt stores neutral when contiguous-per-instruction.
//  R6: residency-wave stagger neutral.
//  R7: 67.7us REGRESSION: lane-consecutive ownership made L0 stores strided
//      (16B at 32B stride per instr) -> +55MB WRITE_SIZE amplification with
//      nt evict-first. Fix: strided-pair ownership (this round).

#define THREADS 256
#define K1_BLOCKS ((1 << 25) / 1024 / 4)   // 8192 blocks x 4 waves
#define K2THREADS 1024

typedef __attribute__((ext_vector_type(2))) float f2_t;

__device__ __forceinline__ void nt_store2(float a, float b, float* p) {
    f2_t t = {a, b};
    __builtin_nontemporal_store(t, (f2_t*)p);
}
__device__ __forceinline__ void nt_store1(float v, float* p) {
    __builtin_nontemporal_store(v, p);
}

__device__ __forceinline__ void level_params(const float* __restrict__ P, int j,
                                             float& hx, float& hy) {
    float px = P[2 * j], py = P[2 * j + 1];
    float n = fmaxf(sqrtf(px * px + py * py), 1e-12f);
    hx = px / n;  // phi_x
    hy = py / n;  // phi_y   (psi = (phi_y, -phi_x))
}

// blo holds seq[0..64), bhi seq[64..128), one value per lane. Produces the
// pairwise merge seq'[0..64) (one per lane) and nt-stores the detail.
__device__ __forceinline__ float shfl_combine(float blo, float bhi, int lane,
                                              float hx, float hy, float* ddst) {
    float xa = __shfl(blo, (2 * lane) & 63, 64);
    float ya = __shfl(blo, (2 * lane + 1) & 63, 64);
    float xb = __shfl(bhi, (2 * lane) & 63, 64);
    float yb = __shfl(bhi, (2 * lane + 1) & 63, 64);
    float x = (lane < 32) ? xa : xb;
    float y = (lane < 32) ? ya : yb;
    nt_store1(x * hy - y * hx, ddst);
    return x * hx + y * hy;
}

__global__ __launch_bounds__(THREADS, 8)
void wave_k1(const float* __restrict__ f, const float* __restrict__ P,
             float* __restrict__ out) {
    const int lane = threadIdx.x & 63;
    const int wg   = blockIdx.x * 4 + (threadIdx.x >> 6);   // < 32768

    float hx[10], hy[10];
#pragma unroll
    for (int j = 0; j < 10; ++j) level_params(P, j, hx[j], hy[j]);

    // wave owns 1024 elements = 256 float4; lane takes float4 m = lane+64k
    const float4* in4 = reinterpret_cast<const float4*>(f) + (size_t)wg * 256;
    float4 q0 = in4[lane], q1 = in4[lane + 64],
           q2 = in4[lane + 128], q3 = in4[lane + 192];

    float* d0out = out + (1 << 24) + (size_t)wg * 512;   // 2 details per m
    float* d1out = out + (1 << 23) + (size_t)wg * 256;   // 1 detail per m
    float b0, b1, b2, b3;
#define L01(q, k, bout) { \
        float aE = q.x * hx[0] + q.y * hy[0]; \
        float aO = q.z * hx[0] + q.w * hy[0]; \
        nt_store2(q.x * hy[0] - q.y * hx[0], q.z * hy[0] - q.w * hx[0], \
                  d0out + 2 * (lane + 64 * k)); \
        nt_store1(aE * hy[1] - aO * hx[1], d1out + lane + 64 * k); \
        bout = aE * hx[1] + aO * hy[1]; }
    L01(q0, 0, b0) L01(q1, 1, b1) L01(q2, 2, b2) L01(q3, 3, b3)
#undef L01

    // level 2: 256 -> 128 (two reg-pairs)
    float* d2out = out + (1 << 22) + (size_t)wg * 128;
    float c0 = shfl_combine(b0, b1, lane, hx[2], hy[2], d2out + lane);
    float c1 = shfl_combine(b2, b3, lane, hx[2], hy[2], d2out + 64 + lane);

    // level 3: 128 -> 64
    float* d3out = out + (1 << 21) + (size_t)wg * 64;
    float v = shfl_combine(c0, c1, lane, hx[3], hy[3], d3out + lane);

    // levels 4..9: 64 -> 1 shuffle tail
#pragma unroll
    for (int j = 4; j <= 9; ++j) {
        int p = 1 << (9 - j);                 // 32,16,8,4,2,1
        float x = __shfl(v, (2 * lane) & 63, 64);
        float y = __shfl(v, (2 * lane + 1) & 63, 64);
        if (lane < p) out[(1 << (24 - j)) + wg * p + lane] = x * hy[j] - y * hx[j];
        v = x * hx[j] + y * hy[j];
    }
    if (lane == 0) out[wg] = v;               // temp; k2 rewrites [0, 2^15)
}

__global__ __launch_bounds__(K2THREADS)
void wave_k2(const float* __restrict__ P, float* __restrict__ out) {
    __shared__ float S[16];
    const int lane = threadIdx.x & 63;
    const int w    = threadIdx.x >> 6;        // 0..15

    float hx[15], hy[15];                     // levels 10..24 -> idx j-10
#pragma unroll
    for (int j = 0; j < 15; ++j) level_params(P, j + 10, hx[j], hy[j]);

    // wave owns 2048 of 32768 approxes = 512 float4; lane: m = lane+64k, k<8
    const float4* in4 = reinterpret_cast<const float4*>(out) + (size_t)w * 512;
    float4 q[8];
#pragma unroll
    for (int k = 0; k < 8; ++k) q[k] = in4[lane + 64 * k];
    // L10/L11 detail bands overlap the input region [0,2^15): barrier drains
    // all waves' loads (compiler emits vmcnt(0) before s_barrier).
    __syncthreads();

    float* d10out = out + (1 << 14) + (size_t)w * 1024;
    float* d11out = out + (1 << 13) + (size_t)w * 512;
    float b[8];
#pragma unroll
    for (int k = 0; k < 8; ++k) {
        float aE = q[k].x * hx[0] + q[k].y * hy[0];
        float aO = q[k].z * hx[0] + q[k].w * hy[0];
        nt_store2(q[k].x * hy[0] - q[k].y * hx[0],
                  q[k].z * hy[0] - q[k].w * hx[0], d10out + 2 * (lane + 64 * k));
        nt_store1(aE * hy[1] - aO * hx[1], d11out + lane + 64 * k);
        b[k] = aE * hx[1] + aO * hy[1];
    }

    // level 12: 512 -> 256
    float* d12out = out + (1 << 12) + (size_t)w * 256;
    float c0 = shfl_combine(b[0], b[1], lane, hx[2], hy[2], d12out + lane);
    float c1 = shfl_combine(b[2], b[3], lane, hx[2], hy[2], d12out + 64 + lane);
    float c2 = shfl_combine(b[4], b[5], lane, hx[2], hy[2], d12out + 128 + lane);
    float c3 = shfl_combine(b[6], b[7], lane, hx[2], hy[2], d12out + 192 + lane);

    // level 13: 256 -> 128
    float* d13out = out + (1 << 11) + (size_t)w * 128;
    float s0 = shfl_combine(c0, c1, lane, hx[3], hy[3], d13out + lane);
    float s1 = shfl_combine(c2, c3, lane, hx[3], hy[3], d13out + 64 + lane);

    // level 14: 128 -> 64
    float* d14out = out + (1 << 10) + (size_t)w * 64;
    float v = shfl_combine(s0, s1, lane, hx[4], hy[4], d14out + lane);

    // levels 15..20: 64 -> 1 per wave
#pragma unroll
    for (int j = 15; j <= 20; ++j) {
        int p = 1 << (20 - j);                // 32,16,8,4,2,1
        float x = __shfl(v, (2 * lane) & 63, 64);
        float y = __shfl(v, (2 * lane + 1) & 63, 64);
        if (lane < p) out[(1 << (24 - j)) + w * p + lane] = x * hy[j - 10] - y * hx[j - 10];
        v = x * hx[j - 10] + y * hy[j - 10];
    }
    if (lane == 0) S[w] = v;
    __syncthreads();

    // levels 21..24: wave 0, 16 -> 1
    if (w == 0) {
        float t = (lane < 16) ? S[lane] : 0.0f;
#pragma unroll
        for (int j = 21; j <= 24; ++j) {
            int p = 1 << (24 - j);            // 8,4,2,1
            float x = __shfl(t, (2 * lane) & 63, 64);
            float y = __shfl(t, (2 * lane + 1) & 63, 64);
            if (lane < p) out[p + lane] = x * hy[j - 10] - y * hx[j - 10];
            t = x * hx[j - 10] + y * hy[j - 10];
        }
        if (lane == 0) out[0] = t;
    }
}

extern "C" void kernel_launch(void* const* d_in, const int* in_sizes, int n_in,
                              void* d_out, int out_size, void* d_ws, size_t ws_size,
                              hipStream_t stream) {
    const float* f = (const float*)d_in[0];
    const float* P = (const float*)d_in[1];
    float* out = (float*)d_out;

    wave_k1<<<K1_BLOCKS, THREADS, 0, stream>>>(f, P, out);
    wave_k2<<<1, K2THREADS, 0, stream>>>(P, out);
}

// Round 10
// 52.347 us; speedup vs baseline: 1.2938x; 1.0212x over previous
//
#include <hip/hip_runtime.h>
#include <hip/hip_bf16.h>

// 25-level wavelet decomposition, f: 2^25 f32, P: [25,2] f32.
// out layout: out[0]=final approx; detail level j occupies [2^(24-j), 2^(25-j)).
//
// R9: barrier-free k1, wave owns 2048 elements (8 float4/lane, strided-pair):
//   levels 0-1 lane-local, 2-4 via shuffle-combine tree, 5-10 shuffle tail
//   -> per-wave tail amortized over 2x data vs R8; k2 input halves to 16384.
// Wave approx -> out[wg], wg<16384 (temp; k2 rewrites [0,2^14); k1's smallest
// band L10 = [2^14,2^15) doesn't overlap).
// k2: 1 block x 1024 thr, levels 11-24 (wave owns 1024, R8-k1 structure),
//   one barrier after reg-loads (L11+ bands overlap input region).
//
// HISTORY:
//  R2-R4: 465us = __threadfence() L2 writeback storm (not nt stores).
//  R5: nt stores neutral when contiguous-per-instruction (keep).
//  R6: residency-wave stagger neutral. R7: strided stores = +55MB WRITE ampl.
//  R8: contiguity fixed (WRITE back to 131MB); VALUBusy 17->39% with zero
//      time delta => VALU not binding; k1 pinned at ~48us across 4 structures.

#define THREADS 256
#define K1_BLOCKS ((1 << 25) / 2048 / 4)   // 4096 blocks x 4 waves x 2048 elts
#define K2THREADS 1024

typedef __attribute__((ext_vector_type(2))) float f2_t;

__device__ __forceinline__ void nt_store2(float a, float b, float* p) {
    f2_t t = {a, b};
    __builtin_nontemporal_store(t, (f2_t*)p);
}
__device__ __forceinline__ void nt_store1(float v, float* p) {
    __builtin_nontemporal_store(v, p);
}

__device__ __forceinline__ void level_params(const float* __restrict__ P, int j,
                                             float& hx, float& hy) {
    float px = P[2 * j], py = P[2 * j + 1];
    float n = fmaxf(sqrtf(px * px + py * py), 1e-12f);
    hx = px / n;  // phi_x
    hy = py / n;  // phi_y   (psi = (phi_y, -phi_x))
}

// blo holds seq[0..64), bhi seq[64..128), one value per lane. Produces the
// pairwise merge seq'[0..64) (one per lane) and nt-stores the detail.
__device__ __forceinline__ float shfl_combine(float blo, float bhi, int lane,
                                              float hx, float hy, float* ddst) {
    float xa = __shfl(blo, (2 * lane) & 63, 64);
    float ya = __shfl(blo, (2 * lane + 1) & 63, 64);
    float xb = __shfl(bhi, (2 * lane) & 63, 64);
    float yb = __shfl(bhi, (2 * lane + 1) & 63, 64);
    float x = (lane < 32) ? xa : xb;
    float y = (lane < 32) ? ya : yb;
    nt_store1(x * hy - y * hx, ddst);
    return x * hx + y * hy;
}

__global__ __launch_bounds__(THREADS, 4)
void wave_k1(const float* __restrict__ f, const float* __restrict__ P,
             float* __restrict__ out) {
    const int lane = threadIdx.x & 63;
    const int wg   = blockIdx.x * 4 + (threadIdx.x >> 6);   // < 16384

    float hx[11], hy[11];
#pragma unroll
    for (int j = 0; j < 11; ++j) level_params(P, j, hx[j], hy[j]);

    // wave owns 2048 elements = 512 float4; lane takes m = lane + 64k, k<8
    const float4* in4 = reinterpret_cast<const float4*>(f) + (size_t)wg * 512;
    float4 q[8];
#pragma unroll
    for (int k = 0; k < 8; ++k) q[k] = in4[lane + 64 * k];

    float* d0out = out + (1 << 24) + (size_t)wg * 1024;  // 2 details per m
    float* d1out = out + (1 << 23) + (size_t)wg * 512;   // 1 detail per m
    float b[8];
#pragma unroll
    for (int k = 0; k < 8; ++k) {
        float aE = q[k].x * hx[0] + q[k].y * hy[0];
        float aO = q[k].z * hx[0] + q[k].w * hy[0];
        nt_store2(q[k].x * hy[0] - q[k].y * hx[0],
                  q[k].z * hy[0] - q[k].w * hx[0], d0out + 2 * (lane + 64 * k));
        nt_store1(aE * hy[1] - aO * hx[1], d1out + lane + 64 * k);
        b[k] = aE * hx[1] + aO * hy[1];
    }

    // level 2: 512 -> 256
    float* d2out = out + (1 << 22) + (size_t)wg * 256;
    float c0 = shfl_combine(b[0], b[1], lane, hx[2], hy[2], d2out + lane);
    float c1 = shfl_combine(b[2], b[3], lane, hx[2], hy[2], d2out + 64 + lane);
    float c2 = shfl_combine(b[4], b[5], lane, hx[2], hy[2], d2out + 128 + lane);
    float c3 = shfl_combine(b[6], b[7], lane, hx[2], hy[2], d2out + 192 + lane);

    // level 3: 256 -> 128
    float* d3out = out + (1 << 21) + (size_t)wg * 128;
    float s0 = shfl_combine(c0, c1, lane, hx[3], hy[3], d3out + lane);
    float s1 = shfl_combine(c2, c3, lane, hx[3], hy[3], d3out + 64 + lane);

    // level 4: 128 -> 64
    float* d4out = out + (1 << 20) + (size_t)wg * 64;
    float v = shfl_combine(s0, s1, lane, hx[4], hy[4], d4out + lane);

    // levels 5..10: 64 -> 1 shuffle tail
#pragma unroll
    for (int j = 5; j <= 10; ++j) {
        int p = 1 << (10 - j);                // 32,16,8,4,2,1
        float x = __shfl(v, (2 * lane) & 63, 64);
        float y = __shfl(v, (2 * lane + 1) & 63, 64);
        if (lane < p) out[(1 << (24 - j)) + wg * p + lane] = x * hy[j] - y * hx[j];
        v = x * hx[j] + y * hy[j];
    }
    if (lane == 0) out[wg] = v;               // temp; k2 rewrites [0, 2^14)
}

__global__ __launch_bounds__(K2THREADS)
void wave_k2(const float* __restrict__ P, float* __restrict__ out) {
    __shared__ float S[16];
    const int lane = threadIdx.x & 63;
    const int w    = threadIdx.x >> 6;        // 0..15

    float hx[14], hy[14];                     // levels 11..24 -> idx j-11
#pragma unroll
    for (int j = 0; j < 14; ++j) level_params(P, j + 11, hx[j], hy[j]);

    // wave owns 1024 of 16384 approxes = 256 float4; lane: m = lane+64k, k<4
    const float4* in4 = reinterpret_cast<const float4*>(out) + (size_t)w * 256;
    float4 q[4];
#pragma unroll
    for (int k = 0; k < 4; ++k) q[k] = in4[lane + 64 * k];
    // All detail bands below overlap the input region [0,2^14): barrier
    // drains every wave's loads before any store.
    __syncthreads();

    float* d11out = out + (1 << 13) + (size_t)w * 512;
    float* d12out = out + (1 << 12) + (size_t)w * 256;
    float b[4];
#pragma unroll
    for (int k = 0; k < 4; ++k) {
        float aE = q[k].x * hx[0] + q[k].y * hy[0];
        float aO = q[k].z * hx[0] + q[k].w * hy[0];
        nt_store2(q[k].x * hy[0] - q[k].y * hx[0],
                  q[k].z * hy[0] - q[k].w * hx[0], d11out + 2 * (lane + 64 * k));
        nt_store1(aE * hy[1] - aO * hx[1], d12out + lane + 64 * k);
        b[k] = aE * hx[1] + aO * hy[1];
    }

    // level 13: 256 -> 128
    float* d13out = out + (1 << 11) + (size_t)w * 128;
    float c0 = shfl_combine(b[0], b[1], lane, hx[2], hy[2], d13out + lane);
    float c1 = shfl_combine(b[2], b[3], lane, hx[2], hy[2], d13out + 64 + lane);

    // level 14: 128 -> 64
    float* d14out = out + (1 << 10) + (size_t)w * 64;
    float v = shfl_combine(c0, c1, lane, hx[3], hy[3], d14out + lane);

    // levels 15..20: 64 -> 1 per wave
#pragma unroll
    for (int j = 15; j <= 20; ++j) {
        int p = 1 << (20 - j);                // 32,16,8,4,2,1
        float x = __shfl(v, (2 * lane) & 63, 64);
        float y = __shfl(v, (2 * lane + 1) & 63, 64);
        if (lane < p) out[(1 << (24 - j)) + w * p + lane] = x * hy[j - 11] - y * hx[j - 11];
        v = x * hx[j - 11] + y * hy[j - 11];
    }
    if (lane == 0) S[w] = v;
    __syncthreads();

    // levels 21..24: wave 0, 16 -> 1
    if (w == 0) {
        float t = (lane < 16) ? S[lane] : 0.0f;
#pragma unroll
        for (int j = 21; j <= 24; ++j) {
            int p = 1 << (24 - j);            // 8,4,2,1
            float x = __shfl(t, (2 * lane) & 63, 64);
            float y = __shfl(t, (2 * lane + 1) & 63, 64);
            if (lane < p) out[p + lane] = x * hy[j - 11] - y * hx[j - 11];
            t = x * hx[j - 11] + y * hy[j - 11];
        }
        if (lane == 0) out[0] = t;
    }
}

extern "C" void kernel_launch(void* const* d_in, const int* in_sizes, int n_in,
                              void* d_out, int out_size, void* d_ws, size_t ws_size,
                              hipStream_t stream) {
    const float* f = (const float*)d_in[0];
    const float* P = (const float*)d_in[1];
    float* out = (float*)d_out;

    wave_k1<<<K1_BLOCKS, THREADS, 0, stream>>>(f, P, out);
    wave_k2<<<1, K2THREADS, 0, stream>>>(P, out);
}